// Round 4
// baseline (1542.892 us; speedup 1.0000x reference)
//
#include <hip/hip_runtime.h>
#include <cstdint>

#define N_B 4
#define L_S 2048
#define C_F 1024
#define H_N 8
#define D_H 128
#define M_T (N_B * L_S)   // 8192 tokens

typedef __bf16 bf16;
typedef __bf16 bf16x4 __attribute__((ext_vector_type(4)));
typedef __bf16 bf16x8 __attribute__((ext_vector_type(8)));
typedef float f32x4 __attribute__((ext_vector_type(4)));

__device__ __forceinline__ float elup1(float x) {
    return x > 0.0f ? x + 1.0f : __expf(x);
}

// flagged 4-element load: inputs may be bf16 or fp32 (runtime-detected)
__device__ __forceinline__ void load4f(const void* base, size_t e0, int isbf, float* o) {
    if (isbf) {
        bf16x4 v = *(const bf16x4*)((const bf16*)base + e0);
        o[0] = (float)v[0]; o[1] = (float)v[1]; o[2] = (float)v[2]; o[3] = (float)v[3];
    } else {
        float4 v = *(const float4*)((const float*)base + e0);
        o[0] = v.x; o[1] = v.y; o[2] = v.z; o[3] = v.w;
    }
}

// ---------------------------------------------------------------- dtype detect
// e_g1 is all ones. bf16 pair -> 0x3F803F80 ; fp32 -> 0x3F800000
__global__ void detect_dtype(const unsigned int* g1, int* flag) {
    if (threadIdx.x == 0 && blockIdx.x == 0)
        *flag = (g1[0] == 0x3F803F80u) ? 1 : 0;
}

// ---------------------------------------------------------------- transpose
// dst[c*R + r] = (bf16)src[r*Cc + c], src dtype per flag
__global__ __launch_bounds__(256) void transpose_any(
        const void* __restrict__ src, bf16* __restrict__ dst,
        int R, int Cc, const int* __restrict__ flagp) {
    const int isbf = *flagp;
    __shared__ bf16 tile[32][33];
    const int bx = blockIdx.x * 32;   // col
    const int by = blockIdx.y * 32;   // row
    const int tx = threadIdx.x & 31;
    const int ty = threadIdx.x >> 5;  // 0..7
#pragma unroll
    for (int i = 0; i < 32; i += 8) {
        size_t ix = (size_t)(by + ty + i) * Cc + bx + tx;
        float v = isbf ? (float)((const bf16*)src)[ix] : ((const float*)src)[ix];
        tile[ty + i][tx] = (bf16)v;
    }
    __syncthreads();
#pragma unroll
    for (int i = 0; i < 32; i += 8)
        dst[(size_t)(bx + ty + i) * R + by + tx] = tile[tx][ty + i];
}

// ---------------------------------------------------------------- GEMM (B^T)
// C[M,N] (bf16, opt relu) = A[M,K](bf16) @ Bt[N,K]^T, fp32 accum.
template <int RELU>
__global__ __launch_bounds__(256, 2) void gemm_bt(
        const bf16* __restrict__ A, const bf16* __restrict__ Bt,
        bf16* __restrict__ C, int M, int N, int K) {
    __shared__ bf16 sA[128 * 64];
    __shared__ bf16 sB[128 * 64];
    const int t = threadIdx.x;
    const int lane = t & 63;
    const int w = t >> 6;
    const int wm = (w >> 1) * 64, wn = (w & 1) * 64;
    const int lr = lane & 15, lq = lane >> 4;
    const int m0 = blockIdx.y * 128, n0 = blockIdx.x * 128;

    f32x4 acc[4][4] = {};

    for (int kt = 0; kt < K; kt += 64) {
        const bf16* Ag = A + (size_t)m0 * K + kt;
        const bf16* Bg = Bt + (size_t)n0 * K + kt;
        bf16x8 ra[4], rb[4];
#pragma unroll
        for (int i = 0; i < 4; ++i) {
            int ci = t + i * 256;             // 16B chunk id, 0..1023
            int r = ci >> 3, c8 = (ci & 7) * 8;
            ra[i] = *(const bf16x8*)(Ag + (size_t)r * K + c8);
            rb[i] = *(const bf16x8*)(Bg + (size_t)r * K + c8);
        }
        __syncthreads();                       // prev iter's LDS reads done
#pragma unroll
        for (int i = 0; i < 4; ++i) {
            int ci = t + i * 256;
            *(bf16x8*)&sA[ci * 8] = ra[i];
            *(bf16x8*)&sB[ci * 8] = rb[i];
        }
        __syncthreads();
#pragma unroll
        for (int kk = 0; kk < 64; kk += 32) {
            bf16x8 af[4], bfr[4];
#pragma unroll
            for (int mi = 0; mi < 4; ++mi)
                af[mi] = *(const bf16x8*)&sA[(wm + mi * 16 + lr) * 64 + kk + lq * 8];
#pragma unroll
            for (int ni = 0; ni < 4; ++ni)
                bfr[ni] = *(const bf16x8*)&sB[(wn + ni * 16 + lr) * 64 + kk + lq * 8];
#pragma unroll
            for (int mi = 0; mi < 4; ++mi)
#pragma unroll
                for (int ni = 0; ni < 4; ++ni)
                    acc[mi][ni] = __builtin_amdgcn_mfma_f32_16x16x32_bf16(
                        af[mi], bfr[ni], acc[mi][ni], 0, 0, 0);
        }
    }
#pragma unroll
    for (int mi = 0; mi < 4; ++mi)
#pragma unroll
        for (int ni = 0; ni < 4; ++ni)
#pragma unroll
            for (int r = 0; r < 4; ++r) {
                int row = m0 + wm + mi * 16 + lq * 4 + r;
                int col = n0 + wn + ni * 16 + lr;
                float v = acc[mi][ni][r];
                if (RELU) v = fmaxf(v, 0.0f);
                C[(size_t)row * N + col] = (bf16)v;
            }
}

// ---------------------------------------------------------------- attention
__global__ __launch_bounds__(256, 2) void attn_kv(
        const bf16* __restrict__ kb, const bf16* __restrict__ vb,
        float* __restrict__ KVpart, float* __restrict__ KSpart) {
    const int nh = blockIdx.x;      // 32
    const int chunk = blockIdx.y;   // 8
    const int n = nh >> 3, h = nh & 7;
    const int t = threadIdx.x;
    const int d0 = t >> 1, eh = (t & 1) * 64;
    __shared__ float sK[8][128];
    __shared__ float sV[8][128];
    float acc[64] = {};
    float ksum = 0.0f;
    const size_t base = ((size_t)(n * L_S + chunk * 256)) * C_F + h * D_H;
    const int row = (t * 4) >> 7, col = (t * 4) & 127;
    for (int lb = 0; lb < 256; lb += 8) {
        const size_t off = base + (size_t)(lb + row) * C_F + col;
        bf16x4 k4 = *(const bf16x4*)(kb + off);
        bf16x4 v4 = *(const bf16x4*)(vb + off);
#pragma unroll
        for (int q = 0; q < 4; ++q) {
            sK[row][col + q] = elup1((float)k4[q]);
            sV[row][col + q] = (float)v4[q] * (1.0f / L_S);
        }
        __syncthreads();
#pragma unroll
        for (int r = 0; r < 8; ++r) {
            float kd = sK[r][d0];
            if (!(t & 1)) ksum += kd;
            const float4* vv = (const float4*)&sV[r][eh];
#pragma unroll
            for (int j = 0; j < 16; ++j) {
                float4 x = vv[j];
                acc[j * 4 + 0] += kd * x.x;
                acc[j * 4 + 1] += kd * x.y;
                acc[j * 4 + 2] += kd * x.z;
                acc[j * 4 + 3] += kd * x.w;
            }
        }
        __syncthreads();
    }
    float* out = KVpart + ((size_t)(nh * 8 + chunk)) * (D_H * D_H) + d0 * D_H + eh;
#pragma unroll
    for (int j = 0; j < 16; ++j) {
        float4 x;
        x.x = acc[j * 4 + 0]; x.y = acc[j * 4 + 1];
        x.z = acc[j * 4 + 2]; x.w = acc[j * 4 + 3];
        ((float4*)out)[j] = x;
    }
    if (!(t & 1)) KSpart[(nh * 8 + chunk) * D_H + d0] = ksum;
}

__global__ __launch_bounds__(256) void attn_reduce(
        const float* __restrict__ KVpart, const float* __restrict__ KSpart,
        float* __restrict__ KV, float* __restrict__ Ksum) {
    const int nh = blockIdx.x;
    const int t = threadIdx.x;
    const int d0 = t >> 1, eh = (t & 1) * 64;
    const float* in = KVpart + (size_t)nh * 8 * (D_H * D_H) + d0 * D_H + eh;
    float* out = KV + (size_t)nh * (D_H * D_H) + d0 * D_H + eh;
#pragma unroll
    for (int j = 0; j < 16; ++j) {
        float4 s = {0, 0, 0, 0};
#pragma unroll
        for (int c = 0; c < 8; ++c) {
            float4 p = *(const float4*)(in + (size_t)c * (D_H * D_H) + j * 4);
            s.x += p.x; s.y += p.y; s.z += p.z; s.w += p.w;
        }
        ((float4*)out)[j] = s;
    }
    if (!(t & 1)) {
        float s = 0.0f;
#pragma unroll
        for (int c = 0; c < 8; ++c) s += KSpart[(nh * 8 + c) * D_H + d0];
        Ksum[nh * D_H + d0] = s;
    }
}

__global__ __launch_bounds__(128, 2) void attn_out(
        const bf16* __restrict__ qb, const float* __restrict__ KV,
        const float* __restrict__ Ksum, bf16* __restrict__ ab) {
    const int nh = blockIdx.x;     // 32
    const int tile = blockIdx.y;   // 64 tiles of 32 tokens
    const int n = nh >> 3, h = nh & 7;
    const int t = threadIdx.x;
    __shared__ float Qs[32][129];
    __shared__ float Ks[128];
    __shared__ float Zp[32][4];
    __shared__ float Zs[32];
    __shared__ float KVs[32][128];

    Ks[t] = Ksum[nh * D_H + t];
    const size_t qbase = ((size_t)(n * L_S + tile * 32)) * C_F + h * D_H;
#pragma unroll 4
    for (int r = 0; r < 32; ++r)
        Qs[r][t] = elup1((float)qb[qbase + (size_t)r * C_F + t]);
    __syncthreads();
    {
        int tk4 = t >> 2, seg = (t & 3) * 32;
        float p = 0.0f;
#pragma unroll 8
        for (int d = 0; d < 32; ++d) p += Qs[tk4][seg + d] * Ks[seg + d];
        Zp[tk4][t & 3] = p;
    }
    __syncthreads();
    if (t < 32) Zs[t] = 1.0f / (Zp[t][0] + Zp[t][1] + Zp[t][2] + Zp[t][3] + 1e-6f);
    __syncthreads();

    float acc[32] = {};
    const int tk = t >> 2, s4 = (t & 3) * 4;
    for (int dt = 0; dt < 128; dt += 32) {
        __syncthreads();
#pragma unroll
        for (int i = 0; i < 8; ++i) {   // stage KVs[32][128]
            int ft = t + i * 128;
            ((float4*)KVs)[ft] =
                ((const float4*)(KV + (size_t)nh * (D_H * D_H) + (size_t)dt * D_H))[ft];
        }
        __syncthreads();
        for (int dd = 0; dd < 32; ++dd) {
            float q = Qs[tk][dt + dd];
#pragma unroll
            for (int j = 0; j < 8; ++j) {
                float4 kv = *(const float4*)&KVs[dd][s4 + j * 16];
                acc[j * 4 + 0] += q * kv.x;
                acc[j * 4 + 1] += q * kv.y;
                acc[j * 4 + 2] += q * kv.z;
                acc[j * 4 + 3] += q * kv.w;
            }
        }
    }
    __syncthreads();
    const float z = Zs[tk] * (float)L_S;
    bf16* op = ab + ((size_t)(n * L_S + tile * 32 + tk)) * C_F + h * D_H;
#pragma unroll
    for (int j = 0; j < 8; ++j) {
        bf16x4 o;
        o[0] = (bf16)(acc[j * 4 + 0] * z);
        o[1] = (bf16)(acc[j * 4 + 1] * z);
        o[2] = (bf16)(acc[j * 4 + 2] * z);
        o[3] = (bf16)(acc[j * 4 + 3] * z);
        *(bf16x4*)(op + s4 + j * 16) = o;
    }
}

// ---------------------------------------------------------------- LN + residual
// F32OUT=0: xout(bf16) = bf16( xin + layernorm(msg)*g + b )
// F32OUT=1: xout(fp32) =        xin + layernorm(msg)*g + b     (final output)
template <int F32OUT>
__global__ __launch_bounds__(256) void ln_res(
        const bf16* __restrict__ msg, const void* __restrict__ g,
        const void* __restrict__ bb, const int* __restrict__ flagp,
        const bf16* __restrict__ xin, void* __restrict__ xout) {
    const int isbf = *flagp;
    const int row = blockIdx.x;
    const int t = threadIdx.x;
    const size_t ix = (size_t)row * C_F + t * 4;
    bf16x4 m4 = *(const bf16x4*)(msg + ix);
    float v0 = (float)m4[0], v1 = (float)m4[1], v2 = (float)m4[2], v3 = (float)m4[3];
    float s1 = v0 + v1 + v2 + v3;
    float s2 = v0 * v0 + v1 * v1 + v2 * v2 + v3 * v3;
#pragma unroll
    for (int off = 32; off > 0; off >>= 1) {
        s1 += __shfl_down(s1, off);
        s2 += __shfl_down(s2, off);
    }
    __shared__ float r1[4], r2[4], mv[2];
    const int w = t >> 6, lane = t & 63;
    if (lane == 0) { r1[w] = s1; r2[w] = s2; }
    __syncthreads();
    if (t == 0) {
        float a = r1[0] + r1[1] + r1[2] + r1[3];
        float b2 = r2[0] + r2[1] + r2[2] + r2[3];
        float mean = a / C_F;
        float var = b2 / C_F - mean * mean;
        mv[0] = mean;
        mv[1] = rsqrtf(var + 1e-5f);
    }
    __syncthreads();
    const float mean = mv[0], rs = mv[1];
    float ga[4], ba[4];
    load4f(g, (size_t)t * 4, isbf, ga);
    load4f(bb, (size_t)t * 4, isbf, ba);
    bf16x4 x4 = *(const bf16x4*)(xin + ix);
    float vv[4] = {v0, v1, v2, v3};
    if (F32OUT) {
        float4 of;
        float* op = &of.x;
#pragma unroll
        for (int q = 0; q < 4; ++q) {
            float ln = (vv[q] - mean) * rs * ga[q] + ba[q];
            op[q] = (float)x4[q] + ln;
        }
        *(float4*)((float*)xout + ix) = of;
    } else {
        bf16x4 ob;
#pragma unroll
        for (int q = 0; q < 4; ++q) {
            float ln = (vv[q] - mean) * rs * ga[q] + ba[q];
            ob[q] = (bf16)((float)x4[q] + ln);
        }
        *(bf16x4*)((bf16*)xout + ix) = ob;
    }
}

// ---------------------------------------------------------------- init / convert
__global__ __launch_bounds__(256) void init_ctx_kernel(
        const void* __restrict__ a, const void* __restrict__ b,
        const int* __restrict__ flagp, bf16* __restrict__ xb) {
    const int isbf = *flagp;
    const size_t i = ((size_t)blockIdx.x * 256 + threadIdx.x) * 4;
    float av[4], bv[4];
    load4f(a, i, isbf, av);
    load4f(b, i, isbf, bv);
    bf16x4 o;
#pragma unroll
    for (int q = 0; q < 4; ++q) o[q] = (bf16)(av[q] + bv[q]);
    *(bf16x4*)(xb + i) = o;
}

__global__ __launch_bounds__(256) void conv_copy_kernel(
        const void* __restrict__ a, const int* __restrict__ flagp,
        bf16* __restrict__ xb) {
    const int isbf = *flagp;
    const size_t i = ((size_t)blockIdx.x * 256 + threadIdx.x) * 4;
    float av[4];
    load4f(a, i, isbf, av);
    bf16x4 o;
#pragma unroll
    for (int q = 0; q < 4; ++q) o[q] = (bf16)av[q];
    *(bf16x4*)(xb + i) = o;
}

// ---------------------------------------------------------------- launch
// Workspace map (MB), total ~103.1:
//   [  0, 16) xb    bf16 residual stream
//   [ 16, 32) ctxb  encoder output
//   [ 32, 48) qb    (also msg)
//   [ 48, 64) kb    \__ FFN hidden hb = [48,80)
//   [ 64, 80) vb    /
//   [ 80, 96) S     KVpart -> attn out -> FFN out
//   [ 96,100) TW    per-GEMM transposed weight (JIT)
//   [100    ) KSpart(128K) ; [101,103) KV ; [103) Ksum(16K) ; flag
extern "C" void kernel_launch(void* const* d_in, const int* in_sizes, int n_in,
                              void* d_out, int out_size, void* d_ws, size_t ws_size,
                              hipStream_t stream) {
    const size_t MB = 1u << 20;
    uint8_t* W = (uint8_t*)d_ws;
    bf16* xb    = (bf16*)(W + 0);
    bf16* ctxb  = (bf16*)(W + 16 * MB);
    bf16* qb    = (bf16*)(W + 32 * MB);
    bf16* kb    = (bf16*)(W + 48 * MB);
    bf16* vb    = (bf16*)(W + 64 * MB);
    bf16* hb    = kb;                            // 32 MB FFN hidden = kb|vb
    bf16* S     = (bf16*)(W + 80 * MB);          // 16 MB multi-purpose
    bf16* TW    = (bf16*)(W + 96 * MB);          // 4 MB
    float* KVpart = (float*)S;
    float* KSpart = (float*)(W + 100 * MB);      // 128 KB
    float* KV     = (float*)(W + 101 * MB);      // 2 MB
    float* Ksum   = (float*)(W + 103 * MB);      // 16 KB
    int*   flag   = (int*)(W + 103 * MB + 64 * 1024);

    detect_dtype<<<1, 64, 0, stream>>>((const unsigned int*)d_in[9], flag);

    auto T = [&](int idx, int R, int Cc) {
        dim3 g(Cc / 32, R / 32);
        transpose_any<<<g, 256, 0, stream>>>(d_in[idx], TW, R, Cc, flag);
    };
    auto G = [&](const bf16* A, bf16* Cc, int Nn, int Kk, bool relu) {
        dim3 g(Nn / 128, M_T / 128);
        if (relu) gemm_bt<1><<<g, 256, 0, stream>>>(A, TW, Cc, M_T, Nn, Kk);
        else      gemm_bt<0><<<g, 256, 0, stream>>>(A, TW, Cc, M_T, Nn, Kk);
    };
    auto TG = [&](int idx, const bf16* A, bf16* Cc, int Nn, int Kk, bool relu) {
        T(idx, Kk, Nn);   // weight stored [K,N] row-major -> TW = [N][K]
        G(A, Cc, Nn, Kk, relu);
    };
    auto ATT = [&](const bf16* q, const bf16* k, const bf16* v, bf16* o) {
        attn_kv<<<dim3(32, 8), 256, 0, stream>>>(k, v, KVpart, KSpart);
        attn_reduce<<<32, 256, 0, stream>>>(KVpart, KSpart, KV, Ksum);
        attn_out<<<dim3(32, 64), 128, 0, stream>>>(q, KV, Ksum, o);
    };
    auto LN = [&](const bf16* m, int gi, int bi, const bf16* xi, bf16* xo) {
        ln_res<0><<<M_T, 256, 0, stream>>>(m, d_in[gi], d_in[bi], flag, xi, (void*)xo);
    };

    // ---------------- encoder: x = ctx = context + pos
    init_ctx_kernel<<<M_T * C_F / 1024, 256, 0, stream>>>(d_in[1], d_in[2], flag, xb);
    TG(3, xb, qb, C_F, C_F, false);          // q = x @ e_wq
    TG(4, xb, kb, C_F, C_F, false);          // k
    TG(5, xb, vb, C_F, C_F, false);          // v
    ATT(qb, kb, vb, S);                      // S = attn out
    TG(6, S, qb, C_F, C_F, false);           // qb := msg = attn @ e_wm
    LN(qb, 9, 10, xb, xb);                   // x += ln(msg)
    TG(7, xb, hb, 2 * C_F, C_F, true);       // hb = relu(x @ w1)
    TG(8, hb, S, C_F, 2 * C_F, false);       // S := hb @ w2
    LN(S, 11, 12, xb, ctxb);                 // ctx done -> ctxb

    // ---------------- decoder: x = depth_feat
    conv_copy_kernel<<<M_T * C_F / 1024, 256, 0, stream>>>(d_in[0], flag, xb);
    TG(13, xb, qb, C_F, C_F, false);
    TG(14, xb, kb, C_F, C_F, false);
    TG(15, xb, vb, C_F, C_F, false);
    ATT(qb, kb, vb, S);
    TG(16, S, qb, C_F, C_F, false);          // msg = attn @ d_wm0
    LN(qb, 23, 24, xb, xb);
    TG(17, xb, qb, C_F, C_F, false);         // q1 from updated x
    TG(18, ctxb, kb, C_F, C_F, false);       // k1 from ctx
    TG(19, ctxb, vb, C_F, C_F, false);       // v1 from ctx
    ATT(qb, kb, vb, S);
    TG(20, S, qb, C_F, C_F, false);          // msg = attn @ d_wm1
    LN(qb, 25, 26, xb, xb);
    TG(21, xb, hb, 2 * C_F, C_F, true);
    TG(22, hb, S, C_F, 2 * C_F, false);
    // final LN writes FP32 directly to d_out (reference output dtype = float32)
    ln_res<1><<<M_T, 256, 0, stream>>>(S, d_in[27], d_in[28], flag, xb, d_out);
}

// Round 5
// 1102.850 us; speedup vs baseline: 1.3990x; 1.3990x over previous
//
#include <hip/hip_runtime.h>
#include <cstdint>

#define N_B 4
#define L_S 2048
#define C_F 1024
#define H_N 8
#define D_H 128
#define M_T (N_B * L_S)   // 8192 tokens

typedef __bf16 bf16;
typedef __bf16 bf16x4 __attribute__((ext_vector_type(4)));
typedef __bf16 bf16x8 __attribute__((ext_vector_type(8)));
typedef float f32x4 __attribute__((ext_vector_type(4)));

typedef __attribute__((address_space(1))) void gvoid_t;
typedef __attribute__((address_space(3))) void lvoid_t;

__device__ __forceinline__ void lds_cp16(void* lds, const void* g) {
    __builtin_amdgcn_global_load_lds((gvoid_t*)g, (lvoid_t*)lds, 16, 0, 0);
}

__device__ __forceinline__ float elup1(float x) {
    return x > 0.0f ? x + 1.0f : __expf(x);
}

__device__ __forceinline__ void load4f(const void* base, size_t e0, int isbf, float* o) {
    if (isbf) {
        bf16x4 v = *(const bf16x4*)((const bf16*)base + e0);
        o[0] = (float)v[0]; o[1] = (float)v[1]; o[2] = (float)v[2]; o[3] = (float)v[3];
    } else {
        float4 v = *(const float4*)((const float*)base + e0);
        o[0] = v.x; o[1] = v.y; o[2] = v.z; o[3] = v.w;
    }
}

// ---------------------------------------------------------------- dtype detect
__global__ void detect_dtype(const unsigned int* g1, int* flag) {
    if (threadIdx.x == 0 && blockIdx.x == 0)
        *flag = (g1[0] == 0x3F803F80u) ? 1 : 0;
}

// ---------------------------------------------------------------- transpose (JIT fallback)
__global__ __launch_bounds__(256) void transpose_any(
        const void* __restrict__ src, bf16* __restrict__ dst,
        int R, int Cc, const int* __restrict__ flagp) {
    const int isbf = *flagp;
    __shared__ bf16 tile[32][33];
    const int bx = blockIdx.x * 32;
    const int by = blockIdx.y * 32;
    const int tx = threadIdx.x & 31;
    const int ty = threadIdx.x >> 5;
#pragma unroll
    for (int i = 0; i < 32; i += 8) {
        size_t ix = (size_t)(by + ty + i) * Cc + bx + tx;
        float v = isbf ? (float)((const bf16*)src)[ix] : ((const float*)src)[ix];
        tile[ty + i][tx] = (bf16)v;
    }
    __syncthreads();
#pragma unroll
    for (int i = 0; i < 32; i += 8)
        dst[(size_t)(bx + ty + i) * R + by + tx] = tile[tx][ty + i];
}

// ---------------------------------------------------------------- batched transpose
struct TAll {
    const void* src[16];
    unsigned int dstoff[16];   // element offsets into twall
    int R[16];
    int C[16];
    int tile0[17];             // cumulative tile counts
};

__global__ __launch_bounds__(256) void transpose_all(
        TAll p, bf16* __restrict__ twall, const int* __restrict__ flagp) {
    const int isbf = *flagp;
    int gid = blockIdx.x;
    int w = 0;
    while (gid >= p.tile0[w + 1]) ++w;
    const int local = gid - p.tile0[w];
    const int R = p.R[w], Cc = p.C[w];
    const int tilesx = Cc >> 5;
    const int bx = (local % tilesx) * 32;
    const int by = (local / tilesx) * 32;
    const void* src = p.src[w];
    bf16* dst = twall + p.dstoff[w];
    __shared__ bf16 tile[32][33];
    const int tx = threadIdx.x & 31;
    const int ty = threadIdx.x >> 5;
#pragma unroll
    for (int i = 0; i < 32; i += 8) {
        size_t ix = (size_t)(by + ty + i) * Cc + bx + tx;
        float v = isbf ? (float)((const bf16*)src)[ix] : ((const float*)src)[ix];
        tile[ty + i][tx] = (bf16)v;
    }
    __syncthreads();
#pragma unroll
    for (int i = 0; i < 32; i += 8)
        dst[(size_t)(bx + ty + i) * R + by + tx] = tile[tx][ty + i];
}

// ---------------------------------------------------------------- GEMM (B^T), global_load_lds staging
template <int RELU>
__global__ __launch_bounds__(256, 2) void gemm_bt(
        const bf16* __restrict__ A, const bf16* __restrict__ Bt,
        bf16* __restrict__ C, int M, int N, int K) {
    __shared__ bf16 sA[128 * 64];
    __shared__ bf16 sB[128 * 64];
    const int t = threadIdx.x;
    const int lane = t & 63;
    const int w = t >> 6;
    const int wm = (w >> 1) * 64, wn = (w & 1) * 64;
    const int lr = lane & 15, lq = lane >> 4;
    const int m0 = blockIdx.y * 128, n0 = blockIdx.x * 128;

    f32x4 acc[4][4] = {};

    for (int kt = 0; kt < K; kt += 64) {
        const bf16* Ag = A + (size_t)m0 * K + kt;
        const bf16* Bg = Bt + (size_t)n0 * K + kt;
#pragma unroll
        for (int i = 0; i < 4; ++i) {
            int ci = t + i * 256;
            int r = ci >> 3, c8 = (ci & 7) * 8;
            lds_cp16(&sA[ci * 8], Ag + (size_t)r * K + c8);
        }
#pragma unroll
        for (int i = 0; i < 4; ++i) {
            int ci = t + i * 256;
            int r = ci >> 3, c8 = (ci & 7) * 8;
            lds_cp16(&sB[ci * 8], Bg + (size_t)r * K + c8);
        }
        __syncthreads();
#pragma unroll
        for (int kk = 0; kk < 64; kk += 32) {
            bf16x8 af[4], bfr[4];
#pragma unroll
            for (int mi = 0; mi < 4; ++mi)
                af[mi] = *(const bf16x8*)&sA[(wm + mi * 16 + lr) * 64 + kk + lq * 8];
#pragma unroll
            for (int ni = 0; ni < 4; ++ni)
                bfr[ni] = *(const bf16x8*)&sB[(wn + ni * 16 + lr) * 64 + kk + lq * 8];
#pragma unroll
            for (int mi = 0; mi < 4; ++mi)
#pragma unroll
                for (int ni = 0; ni < 4; ++ni)
                    acc[mi][ni] = __builtin_amdgcn_mfma_f32_16x16x32_bf16(
                        af[mi], bfr[ni], acc[mi][ni], 0, 0, 0);
        }
        __syncthreads();
    }
#pragma unroll
    for (int mi = 0; mi < 4; ++mi)
#pragma unroll
        for (int ni = 0; ni < 4; ++ni)
#pragma unroll
            for (int r = 0; r < 4; ++r) {
                int row = m0 + wm + mi * 16 + lq * 4 + r;
                int col = n0 + wn + ni * 16 + lr;
                float v = acc[mi][ni][r];
                if (RELU) v = fmaxf(v, 0.0f);
                C[(size_t)row * N + col] = (bf16)v;
            }
}

// ---------------------------------------------------------------- attention
// KV[d][e] = sum_l elup1(K[l][d]) * V[l][e]   (no 1/L -- cancels with *L later)
// Stage 1: grid (nh=32, chunk=16), chunk = 128 rows, bf16 partials.
__global__ __launch_bounds__(256) void attn_kv(
        const bf16* __restrict__ kb, const bf16* __restrict__ vb,
        bf16* __restrict__ KVp, float* __restrict__ KSp) {
    const int nh = blockIdx.x;      // 32
    const int chunk = blockIdx.y;   // 16
    const int n = nh >> 3, h = nh & 7;
    const int t = threadIdx.x;
    const int d0 = t >> 1, eh = (t & 1) * 64;
    const int srow = t >> 5, scol = (t & 31) * 4;
    __shared__ float sK[8][128];
    __shared__ float sV[8][128];
    float acc[64] = {};
    float ksum = 0.0f;
    const size_t base = ((size_t)(n * L_S + chunk * 128)) * C_F + h * D_H;
    for (int lb = 0; lb < 128; lb += 8) {
        const size_t off = base + (size_t)(lb + srow) * C_F + scol;
        bf16x4 k4 = *(const bf16x4*)(kb + off);
        bf16x4 v4 = *(const bf16x4*)(vb + off);
        float4 ek, fv;
        ek.x = elup1((float)k4[0]); ek.y = elup1((float)k4[1]);
        ek.z = elup1((float)k4[2]); ek.w = elup1((float)k4[3]);
        fv.x = (float)v4[0]; fv.y = (float)v4[1];
        fv.z = (float)v4[2]; fv.w = (float)v4[3];
        __syncthreads();              // previous iteration's reads done
        *(float4*)&sK[srow][scol] = ek;
        *(float4*)&sV[srow][scol] = fv;
        __syncthreads();
#pragma unroll
        for (int r = 0; r < 8; ++r) {
            float kd = sK[r][d0];
            if (!(t & 1)) ksum += kd;
            const float4* vv = (const float4*)&sV[r][eh];
#pragma unroll
            for (int j = 0; j < 16; ++j) {
                float4 x = vv[j];
                acc[j * 4 + 0] += kd * x.x;
                acc[j * 4 + 1] += kd * x.y;
                acc[j * 4 + 2] += kd * x.z;
                acc[j * 4 + 3] += kd * x.w;
            }
        }
    }
    bf16* out = KVp + ((size_t)(nh * 16 + chunk)) * (D_H * D_H) + d0 * D_H + eh;
#pragma unroll
    for (int j = 0; j < 16; ++j) {
        bf16x4 o;
        o[0] = (bf16)acc[j * 4 + 0]; o[1] = (bf16)acc[j * 4 + 1];
        o[2] = (bf16)acc[j * 4 + 2]; o[3] = (bf16)acc[j * 4 + 3];
        *(bf16x4*)(out + j * 4) = o;
    }
    if (!(t & 1)) KSp[(nh * 16 + chunk) * D_H + d0] = ksum;
}

// Stage 2: reduce 16 chunks; emit KVt[e][d] (bf16, B-fragment-ready) + Ksum fp32
__global__ __launch_bounds__(256) void attn_reduce(
        const bf16* __restrict__ KVp, const float* __restrict__ KSp,
        bf16* __restrict__ KVt, float* __restrict__ Ksum) {
    const int nh = blockIdx.x;    // 32
    const int es = blockIdx.y;    // 4 e-slabs of 32
    const int t = threadIdx.x;
    const int d = t >> 1, e16 = (t & 1) * 16;
    float fa[16] = {};
    for (int c = 0; c < 16; ++c) {
        const bf16* p = KVp + ((size_t)(nh * 16 + c)) * (D_H * D_H) + d * D_H + es * 32 + e16;
        bf16x8 a = *(const bf16x8*)p;
        bf16x8 b = *(const bf16x8*)(p + 8);
#pragma unroll
        for (int m = 0; m < 8; ++m) { fa[m] += (float)a[m]; fa[8 + m] += (float)b[m]; }
    }
    __shared__ bf16 sT[32][136];
#pragma unroll
    for (int m = 0; m < 16; ++m) sT[e16 + m][d] = (bf16)fa[m];
    __syncthreads();
    const int er = t >> 3, dseg = (t & 7) * 16;
    bf16x8 a = *(const bf16x8*)&sT[er][dseg];
    bf16x8 b = *(const bf16x8*)&sT[er][dseg + 8];
    bf16* o = KVt + (size_t)nh * (D_H * D_H) + (es * 32 + er) * D_H + dseg;
    *(bf16x8*)o = a;
    *(bf16x8*)(o + 8) = b;
    if (es == 0 && t < 128) {
        float s = 0.0f;
#pragma unroll
        for (int c = 0; c < 16; ++c) s += KSp[(nh * 16 + c) * D_H + t];
        Ksum[nh * D_H + t] = s;
    }
}

// Stage 3 (MFMA): out[l][e] = (Qp[l]·KVt[e]) / (Qp[l]·Ksum + eps)
// grid (nh=32, ltile=16 of 128 tokens), 256 thr.
__global__ __launch_bounds__(256, 2) void attn_out_mfma(
        const bf16* __restrict__ qb, const bf16* __restrict__ KVt,
        const float* __restrict__ Ksum, bf16* __restrict__ ab) {
    const int nh = blockIdx.x, tile = blockIdx.y;
    const int n = nh >> 3, h = nh & 7;
    const int t = threadIdx.x;
    const int lane = t & 63;
    const int w = t >> 6;
    const int wm = (w >> 1) * 64, wn = (w & 1) * 64;
    const int lr = lane & 15, lq = lane >> 4;
    __shared__ bf16 sA[128 * 64];
    __shared__ bf16 sB[128 * 64];
    __shared__ float sKs[128];
    __shared__ float sZp[128][2];
    __shared__ float sZ[128];
    if (t < 128) sKs[t] = Ksum[nh * D_H + t];

    f32x4 acc[4][4] = {};
    float zacc = 0.0f;
    const int zrow = t >> 1, zoff = (t & 1) * 32;
    const size_t qbase = ((size_t)(n * L_S + tile * 128)) * C_F + h * D_H;

    for (int kt = 0; kt < 128; kt += 64) {
        bf16x8 qv[4];
#pragma unroll
        for (int i = 0; i < 4; ++i) {
            int ci = t + i * 256;
            int r = ci >> 3, c8 = (ci & 7) * 8;
            bf16x8 q8 = *(const bf16x8*)(qb + qbase + (size_t)r * C_F + kt + c8);
#pragma unroll
            for (int m = 0; m < 8; ++m) q8[m] = (bf16)elup1((float)q8[m]);
            qv[i] = q8;
        }
        __syncthreads();              // previous iteration's LDS reads done
#pragma unroll
        for (int i = 0; i < 4; ++i) {
            int ci = t + i * 256;
            int r = ci >> 3, c8 = (ci & 7) * 8;
            lds_cp16(&sB[ci * 8], KVt + (size_t)nh * (D_H * D_H) + (size_t)r * D_H + kt + c8);
            *(bf16x8*)&sA[ci * 8] = qv[i];
        }
        __syncthreads();
        // Z partial (Qp . Ksum)
#pragma unroll 8
        for (int j = 0; j < 32; ++j)
            zacc += (float)sA[zrow * 64 + zoff + j] * sKs[kt + zoff + j];
#pragma unroll
        for (int kk = 0; kk < 64; kk += 32) {
            bf16x8 af[4], bfr[4];
#pragma unroll
            for (int mi = 0; mi < 4; ++mi)
                af[mi] = *(const bf16x8*)&sA[(wm + mi * 16 + lr) * 64 + kk + lq * 8];
#pragma unroll
            for (int ni = 0; ni < 4; ++ni)
                bfr[ni] = *(const bf16x8*)&sB[(wn + ni * 16 + lr) * 64 + kk + lq * 8];
#pragma unroll
            for (int mi = 0; mi < 4; ++mi)
#pragma unroll
                for (int ni = 0; ni < 4; ++ni)
                    acc[mi][ni] = __builtin_amdgcn_mfma_f32_16x16x32_bf16(
                        af[mi], bfr[ni], acc[mi][ni], 0, 0, 0);
        }
    }
    sZp[zrow][t & 1] = zacc;
    __syncthreads();
    if (t < 128) sZ[t] = 1.0f / (sZp[t][0] + sZp[t][1] + 1e-6f);
    __syncthreads();
#pragma unroll
    for (int mi = 0; mi < 4; ++mi)
#pragma unroll
        for (int ni = 0; ni < 4; ++ni)
#pragma unroll
            for (int r = 0; r < 4; ++r) {
                int row = wm + mi * 16 + lq * 4 + r;
                int col = wn + ni * 16 + lr;
                ab[qbase + (size_t)row * C_F + col] = (bf16)(acc[mi][ni][r] * sZ[row]);
            }
}

// ---------------------------------------------------------------- LN + residual (wave-per-row)
template <int F32OUT>
__global__ __launch_bounds__(256) void ln_res(
        const bf16* __restrict__ msg, const void* __restrict__ g,
        const void* __restrict__ bb, const int* __restrict__ flagp,
        const bf16* __restrict__ xin, void* __restrict__ xout) {
    const int isbf = *flagp;
    const int row = blockIdx.x * 4 + (threadIdx.x >> 6);
    const int lane = threadIdx.x & 63;
    const size_t base = (size_t)row * C_F;
    float m[16];
#pragma unroll
    for (int k = 0; k < 4; ++k) {
        bf16x4 v = *(const bf16x4*)(msg + base + k * 256 + lane * 4);
        m[k * 4 + 0] = (float)v[0]; m[k * 4 + 1] = (float)v[1];
        m[k * 4 + 2] = (float)v[2]; m[k * 4 + 3] = (float)v[3];
    }
    float s1 = 0.0f, s2 = 0.0f;
#pragma unroll
    for (int q = 0; q < 16; ++q) { s1 += m[q]; s2 += m[q] * m[q]; }
#pragma unroll
    for (int off = 32; off > 0; off >>= 1) {
        s1 += __shfl_down(s1, off);
        s2 += __shfl_down(s2, off);
    }
    s1 = __shfl(s1, 0);
    s2 = __shfl(s2, 0);
    const float mean = s1 / C_F;
    const float rs = rsqrtf(s2 / C_F - mean * mean + 1e-5f);
#pragma unroll
    for (int k = 0; k < 4; ++k) {
        const size_t cix = k * 256 + lane * 4;
        float ga[4], ba[4];
        load4f(g, cix, isbf, ga);
        load4f(bb, cix, isbf, ba);
        bf16x4 x4 = *(const bf16x4*)(xin + base + cix);
        if (F32OUT) {
            float4 of;
            of.x = (float)x4[0] + (m[k * 4 + 0] - mean) * rs * ga[0] + ba[0];
            of.y = (float)x4[1] + (m[k * 4 + 1] - mean) * rs * ga[1] + ba[1];
            of.z = (float)x4[2] + (m[k * 4 + 2] - mean) * rs * ga[2] + ba[2];
            of.w = (float)x4[3] + (m[k * 4 + 3] - mean) * rs * ga[3] + ba[3];
            *(float4*)((float*)xout + base + cix) = of;
        } else {
            bf16x4 ob;
            ob[0] = (bf16)((float)x4[0] + (m[k * 4 + 0] - mean) * rs * ga[0] + ba[0]);
            ob[1] = (bf16)((float)x4[1] + (m[k * 4 + 1] - mean) * rs * ga[1] + ba[1]);
            ob[2] = (bf16)((float)x4[2] + (m[k * 4 + 2] - mean) * rs * ga[2] + ba[2]);
            ob[3] = (bf16)((float)x4[3] + (m[k * 4 + 3] - mean) * rs * ga[3] + ba[3]);
            *(bf16x4*)((bf16*)xout + base + cix) = ob;
        }
    }
}

// ---------------------------------------------------------------- init / convert
__global__ __launch_bounds__(256) void init_ctx_kernel(
        const void* __restrict__ a, const void* __restrict__ b,
        const int* __restrict__ flagp, bf16* __restrict__ xb) {
    const int isbf = *flagp;
    const size_t i = ((size_t)blockIdx.x * 256 + threadIdx.x) * 4;
    float av[4], bv[4];
    load4f(a, i, isbf, av);
    load4f(b, i, isbf, bv);
    bf16x4 o;
#pragma unroll
    for (int q = 0; q < 4; ++q) o[q] = (bf16)(av[q] + bv[q]);
    *(bf16x4*)(xb + i) = o;
}

__global__ __launch_bounds__(256) void conv_copy_kernel(
        const void* __restrict__ a, const int* __restrict__ flagp,
        bf16* __restrict__ xb) {
    const int isbf = *flagp;
    const size_t i = ((size_t)blockIdx.x * 256 + threadIdx.x) * 4;
    float av[4];
    load4f(a, i, isbf, av);
    bf16x4 o;
#pragma unroll
    for (int q = 0; q < 4; ++q) o[q] = (bf16)av[q];
    *(bf16x4*)(xb + i) = o;
}

// ---------------------------------------------------------------- launch
// Workspace (MB):
//   [  0, 16) xb      [ 16, 32) ctxb    [ 32, 48) qb
//   [ 48, 64) kb      [ 64, 80) vb      (hb = kb|vb = [48,80))
//   [ 80, 96) S       bf16 KV partials -> attn out -> FFN out
//   [ 96,100) TW      JIT single-weight (fallback)
//   [100    ) KSpart 256K ; [101) KVt 1M ; [102) Ksum 16K ; flag
//   [104,144) TWall   all transposed weights (only if ws_size >= 145 MB)
extern "C" void kernel_launch(void* const* d_in, const int* in_sizes, int n_in,
                              void* d_out, int out_size, void* d_ws, size_t ws_size,
                              hipStream_t stream) {
    const size_t MB = 1u << 20;
    uint8_t* W = (uint8_t*)d_ws;
    bf16* xb    = (bf16*)(W + 0);
    bf16* ctxb  = (bf16*)(W + 16 * MB);
    bf16* qb    = (bf16*)(W + 32 * MB);
    bf16* kb    = (bf16*)(W + 48 * MB);
    bf16* vb    = (bf16*)(W + 64 * MB);
    bf16* hb    = kb;
    bf16* S     = (bf16*)(W + 80 * MB);
    bf16* TW    = (bf16*)(W + 96 * MB);
    bf16* KVp   = S;
    float* KSp  = (float*)(W + 100 * MB);
    bf16* KVt   = (bf16*)(W + 101 * MB);
    float* Ksum = (float*)(W + 102 * MB);
    int*   flag = (int*)(W + 102 * MB + 64 * 1024);
    bf16* TWall = (bf16*)(W + 104 * MB);
    const bool batched = (ws_size >= 145 * MB);

    detect_dtype<<<1, 64, 0, stream>>>((const unsigned int*)d_in[9], flag);

    // weight table
    const int widx[16] = {3,4,5,6,7,8,13,14,15,16,17,18,19,20,21,22};
    const int wR[16]   = {1024,1024,1024,1024,1024,2048,1024,1024,1024,1024,
                          1024,1024,1024,1024,1024,2048};
    const int wC[16]   = {1024,1024,1024,1024,2048,1024,1024,1024,1024,1024,
                          1024,1024,1024,1024,2048,1024};
    unsigned int off[16];
    if (batched) {
        TAll p;
        unsigned int acc = 0;
        int tacc = 0;
        for (int i = 0; i < 16; ++i) {
            p.src[i] = d_in[widx[i]];
            p.dstoff[i] = acc;
            p.R[i] = wR[i];
            p.C[i] = wC[i];
            p.tile0[i] = tacc;
            off[i] = acc;
            acc += (unsigned int)wR[i] * wC[i];
            tacc += (wR[i] / 32) * (wC[i] / 32);
        }
        p.tile0[16] = tacc;
        transpose_all<<<tacc, 256, 0, stream>>>(p, TWall, flag);
    }
    auto BT = [&](int idx) -> const bf16* {
        int s = 0;
        for (int i = 0; i < 16; ++i) if (widx[i] == idx) { s = i; break; }
        if (batched) return TWall + off[s];
        dim3 g(wC[s] / 32, wR[s] / 32);
        transpose_any<<<g, 256, 0, stream>>>(d_in[idx], TW, wR[s], wC[s], flag);
        return TW;
    };
    auto TG = [&](int idx, const bf16* A, bf16* Cc, int Nn, int Kk, bool relu) {
        const bf16* Bt = BT(idx);
        dim3 g(Nn / 128, M_T / 128);
        if (relu) gemm_bt<1><<<g, 256, 0, stream>>>(A, Bt, Cc, M_T, Nn, Kk);
        else      gemm_bt<0><<<g, 256, 0, stream>>>(A, Bt, Cc, M_T, Nn, Kk);
    };
    auto ATT = [&](const bf16* q, const bf16* k, const bf16* v, bf16* o) {
        attn_kv<<<dim3(32, 16), 256, 0, stream>>>(k, v, KVp, KSp);
        attn_reduce<<<dim3(32, 4), 256, 0, stream>>>(KVp, KSp, KVt, Ksum);
        attn_out_mfma<<<dim3(32, 16), 256, 0, stream>>>(q, KVt, Ksum, o);
    };
    auto LN = [&](const bf16* m, int gi, int bi, const bf16* xi, bf16* xo) {
        ln_res<0><<<M_T / 4, 256, 0, stream>>>(m, d_in[gi], d_in[bi], flag, xi, (void*)xo);
    };

    // ---------------- encoder
    init_ctx_kernel<<<M_T * C_F / 1024, 256, 0, stream>>>(d_in[1], d_in[2], flag, xb);
    TG(3, xb, qb, C_F, C_F, false);
    TG(4, xb, kb, C_F, C_F, false);
    TG(5, xb, vb, C_F, C_F, false);
    ATT(qb, kb, vb, S);
    TG(6, S, qb, C_F, C_F, false);
    LN(qb, 9, 10, xb, xb);
    TG(7, xb, hb, 2 * C_F, C_F, true);
    TG(8, hb, S, C_F, 2 * C_F, false);
    LN(S, 11, 12, xb, ctxb);

    // ---------------- decoder
    conv_copy_kernel<<<M_T * C_F / 1024, 256, 0, stream>>>(d_in[0], flag, xb);
    TG(13, xb, qb, C_F, C_F, false);
    TG(14, xb, kb, C_F, C_F, false);
    TG(15, xb, vb, C_F, C_F, false);
    ATT(qb, kb, vb, S);
    TG(16, S, qb, C_F, C_F, false);
    LN(qb, 23, 24, xb, xb);
    TG(17, xb, qb, C_F, C_F, false);
    TG(18, ctxb, kb, C_F, C_F, false);
    TG(19, ctxb, vb, C_F, C_F, false);
    ATT(qb, kb, vb, S);
    TG(20, S, qb, C_F, C_F, false);
    LN(qb, 25, 26, xb, xb);
    TG(21, xb, hb, 2 * C_F, C_F, true);
    TG(22, hb, S, C_F, 2 * C_F, false);
    ln_res<1><<<M_T / 4, 256, 0, stream>>>(S, d_in[27], d_in[28], flag, xb, d_out);
}